// Round 1
// baseline (595.784 us; speedup 1.0000x reference)
//
#include <hip/hip_runtime.h>
#include <math.h>

#define HH 56
#define WW 56
#define CC 64
#define BB 4
#define HWA (HH*WW)   // 3136

// ---------- 1. NCHW -> NHWC transpose (x) ----------
__global__ void k_transpose(const float* __restrict__ src, float* __restrict__ dst) {
    __shared__ float tile[64][65];
    int blk = blockIdx.x;              // BB * (HWA/64)
    int b   = blk / (HWA/64);
    int t0  = (blk % (HWA/64)) * 64;
    int tid = threadIdx.x;             // 256
    int p   = tid & 63;
    int q   = tid >> 6;                // 0..3
#pragma unroll
    for (int i = 0; i < 16; ++i) {
        int c = q + 4*i;
        tile[p][c] = src[(b*CC + c)*HWA + t0 + p];   // coalesced over p
    }
    __syncthreads();
    int c2 = tid & 63;
#pragma unroll
    for (int i = 0; i < 16; ++i) {
        int p2 = q + 4*i;
        dst[(b*HWA + t0 + p2)*CC + c2] = tile[p2][c2];  // coalesced over c2
    }
}

// ---------- 2. weight transpose OIHW -> [ky][kx][ic][oc] ----------
__global__ void k_wtrans(const float* __restrict__ w, float* __restrict__ wt, int OC) {
    int i = blockIdx.x*256 + threadIdx.x;
    int n = OC*288;
    if (i >= n) return;
    int kx = i % 3;
    int ky = (i/3) % 3;
    int ic = (i/9) & 31;
    int oc = i / 288;
    wt[((ky*3+kx)*32 + ic)*OC + oc] = w[i];
}

// ---------- 3. grouped 3x3 conv (groups=2), 4 pixels per block ----------
__global__ void k_conv_g2(const float* __restrict__ xt, const float* __restrict__ wt,
                          const float* __restrict__ bias, float* __restrict__ out, int OC) {
    __shared__ float patch[3*6*64];    // rows h-1..h+1, cols w0-1..w0+4, 64 ch
    int blk = blockIdx.x;              // BB*56*14
    int b   = blk / (56*14);
    int rem = blk % (56*14);
    int h   = rem / 14;
    int w0  = (rem % 14) * 4;
    int tid = threadIdx.x;             // 128

    for (int i = tid; i < 1152; i += 128) {
        int c   = i & 63;
        int col = (i >> 6) % 6;
        int r   = i / 384;
        int y = h - 1 + r;
        int x = w0 - 1 + col;
        float v = 0.f;
        if (y >= 0 && y < HH && x >= 0 && x < WW)
            v = xt[(b*HWA + y*WW + x)*CC + c];
        patch[i] = v;
    }
    __syncthreads();

    int oc = tid;
    if (oc < OC) {
        int half  = OC >> 1;
        int cbase = (oc >= half) ? 32 : 0;
        float bs = bias[oc];
        float acc0 = bs, acc1 = bs, acc2 = bs, acc3 = bs;
        for (int ky = 0; ky < 3; ++ky) {
            for (int kx = 0; kx < 3; ++kx) {
                const float* wp = wt + ((ky*3+kx)*32)*OC + oc;
                const float* pp = patch + ky*384 + kx*64 + cbase;
#pragma unroll
                for (int ic = 0; ic < 32; ++ic) {
                    float wv  = wp[ic*OC];      // coalesced over oc lanes
                    acc0 += wv * pp[ic];
                    acc1 += wv * pp[64  + ic];
                    acc2 += wv * pp[128 + ic];
                    acc3 += wv * pp[192 + ic];
                }
            }
        }
        int base = (b*OC + oc)*HWA + h*WW + w0;   // 16B aligned (w0 % 4 == 0)
        float4 r; r.x = acc0; r.y = acc1; r.z = acc2; r.w = acc3;
        *reinterpret_cast<float4*>(out + base) = r;
    }
}

// ---------- 4. deformable depthwise conv, NHWC in/out ----------
template<int K, int KS, int PAD>
__global__ void k_deform(const float* __restrict__ src, const float* __restrict__ off,
                         const float* __restrict__ wg, const float* __restrict__ bias,
                         float* __restrict__ out) {
    __shared__ float lw[K*64];         // [t][c], conflict-free lane reads
    int tid = threadIdx.x + threadIdx.y*64;   // 256
    for (int i = tid; i < K*64; i += 256) {
        int c = i / K, t = i % K;
        lw[t*64 + c] = wg[i];
    }
    __syncthreads();

    int blk = blockIdx.x;              // BB * (HWA/4)
    int b   = blk / (HWA/4);
    int hw  = (blk % (HWA/4))*4 + threadIdx.y;
    int h   = hw / WW, w = hw % WW;
    int c   = threadIdx.x;

    const float* offb = off + (size_t)(b*2*K)*HWA + hw;
    const float* srcb = src + (size_t)b*HWA*CC + c;

    float acc = 0.f;
    for (int t = 0; t < K; ++t) {
        int ky = t / KS, kx = t % KS;
        float oy = offb[(2*t  )*HWA];  // wave-broadcast
        float ox = offb[(2*t+1)*HWA];
        float py = (float)(h - PAD + 3*ky) + oy;
        float px = (float)(w - PAD + 3*kx) + ox;
        float y0f = floorf(py), x0f = floorf(px);
        float ly = py - y0f, lx = px - x0f;
        float hy = 1.f - ly, hx = 1.f - lx;
        int y0 = (int)y0f, x0 = (int)x0f;
        bool yi0 = (y0   >= 0) && (y0   < HH);
        bool yi1 = (y0+1 >= 0) && (y0+1 < HH);
        bool xi0 = (x0   >= 0) && (x0   < WW);
        bool xi1 = (x0+1 >= 0) && (x0+1 < WW);
        float v00 = 0.f, v01 = 0.f, v10 = 0.f, v11 = 0.f;
        int base = (y0*WW + x0)*CC;
        if (yi0 && xi0) v00 = srcb[base];
        if (yi0 && xi1) v01 = srcb[base + CC];
        if (yi1 && xi0) v10 = srcb[base + WW*CC];
        if (yi1 && xi1) v11 = srcb[base + WW*CC + CC];
        float val = hy*(hx*v00 + lx*v01) + ly*(hx*v10 + lx*v11);
        acc += val * lw[t*64 + c];
    }
    out[((size_t)b*HWA + hw)*CC + c] = acc + bias[c];
}

// ---------- 5. global average pool per (b, feat, c) ----------
__global__ void k_gap(const float* __restrict__ o1, const float* __restrict__ o2,
                      float* __restrict__ gap) {
    __shared__ float red[4][64];
    int f = blockIdx.x & 1;
    int b = blockIdx.x >> 1;
    const float* src = f ? o2 : o1;
    int tid = threadIdx.x;             // 256
    int c = tid & 63, s = tid >> 6;
    float sum = 0.f;
    for (int hw = s; hw < HWA; hw += 4)
        sum += src[((size_t)b*HWA + hw)*CC + c];
    red[s][c] = sum;
    __syncthreads();
    if (s == 0) {
        float tot = red[0][c] + red[1][c] + red[2][c] + red[3][c];
        gap[(b*2 + f)*CC + c] = tot * (1.f/HWA);
    }
}

// ---------- 6. softmax gate + combine, NHWC -> NCHW ----------
__global__ void k_combine(const float* __restrict__ o1, const float* __restrict__ o2,
                          const float* __restrict__ gap, float* __restrict__ out) {
    __shared__ float tile[64][65];
    int blk = blockIdx.x;              // BB * (HWA/64)
    int b   = blk / (HWA/64);
    int t0  = (blk % (HWA/64)) * 64;
    int tid = threadIdx.x;             // 256
    int c = tid & 63, q = tid >> 6;

    float g1 = gap[(b*2+0)*CC + c];
    float g2 = gap[(b*2+1)*CC + c];
    float m  = fmaxf(g1, g2);
    float e1 = expf(g1 - m), e2 = expf(g2 - m);
    float a1 = e1 / (e1 + e2), a2 = 1.f - a1;

#pragma unroll
    for (int i = 0; i < 16; ++i) {
        int p = q + 4*i;
        size_t idx = ((size_t)b*HWA + t0 + p)*CC + c;
        tile[p][c] = o1[idx]*a1 + o2[idx]*a2;
    }
    __syncthreads();
    int p2 = tid & 63;
#pragma unroll
    for (int i = 0; i < 16; ++i) {
        int c2 = q + 4*i;
        out[((size_t)b*CC + c2)*HWA + t0 + p2] = tile[p2][c2];
    }
}

extern "C" void kernel_launch(void* const* d_in, const int* in_sizes, int n_in,
                              void* d_out, int out_size, void* d_ws, size_t ws_size,
                              hipStream_t stream) {
    const float* x      = (const float*)d_in[0];
    const float* w_off3 = (const float*)d_in[1];
    const float* b_off3 = (const float*)d_in[2];
    const float* w_off2 = (const float*)d_in[3];
    const float* b_off2 = (const float*)d_in[4];
    const float* w7     = (const float*)d_in[5];
    const float* b7     = (const float*)d_in[6];
    const float* w5     = (const float*)d_in[7];
    const float* b5     = (const float*)d_in[8];
    float* out = (float*)d_out;

    float* ws   = (float*)d_ws;
    float* x_t  = ws;                     // 802816
    float* off3 = x_t  + 802816;          // 1229312
    float* off2 = off3 + 1229312;         // 627200
    float* out1 = off2 + 627200;          // 802816
    float* out2 = out1 + 802816;          // 802816
    float* gap  = out2 + 802816;          // 512
    float* wt3  = gap  + 512;             // 28224
    float* wt2  = wt3  + 28224;           // 14400
    size_t need = (size_t)(802816*3 + 1229312 + 627200 + 512 + 28224 + 14400) * 4;
    if (ws_size < need) return;           // fail loudly via wrong output

    // x -> NHWC
    k_transpose<<<BB*(HWA/64), 256, 0, stream>>>(x, x_t);
    // weight transposes
    k_wtrans<<<(98*288 + 255)/256, 256, 0, stream>>>(w_off3, wt3, 98);
    k_wtrans<<<(50*288 + 255)/256, 256, 0, stream>>>(w_off2, wt2, 50);
    // offset convs
    k_conv_g2<<<BB*56*14, 128, 0, stream>>>(x_t, wt3, b_off3, off3, 98);
    k_conv_g2<<<BB*56*14, 128, 0, stream>>>(x_t, wt2, b_off2, off2, 50);
    // deform 1: k=7, pad=9, dil=3, src = x_t
    k_deform<49,7,9><<<BB*(HWA/4), dim3(64,4), 0, stream>>>(x_t, off3, w7, b7, out1);
    // deform 2: k=5, pad=6, dil=3, src = out1
    k_deform<25,5,6><<<BB*(HWA/4), dim3(64,4), 0, stream>>>(out1, off2, w5, b5, out2);
    // gate
    k_gap<<<BB*2, 256, 0, stream>>>(out1, out2, gap);
    k_combine<<<BB*(HWA/64), 256, 0, stream>>>(out1, out2, gap, out);
}

// Round 2
// 417.101 us; speedup vs baseline: 1.4284x; 1.4284x over previous
//
#include <hip/hip_runtime.h>
#include <math.h>

#define HH 56
#define WW 56
#define CC 64
#define BB 4
#define HWA (HH*WW)   // 3136

// ---------- 1. NCHW -> NHWC transpose (x) ----------
__global__ void k_transpose(const float* __restrict__ src, float* __restrict__ dst) {
    __shared__ float tile[64][65];
    int blk = blockIdx.x;              // BB * (HWA/64)
    int b   = blk / (HWA/64);
    int t0  = (blk % (HWA/64)) * 64;
    int tid = threadIdx.x;             // 256
    int p   = tid & 63;
    int q   = tid >> 6;                // 0..3
#pragma unroll
    for (int i = 0; i < 16; ++i) {
        int c = q + 4*i;
        tile[p][c] = src[(b*CC + c)*HWA + t0 + p];   // coalesced over p
    }
    __syncthreads();
    int c2 = tid & 63;
#pragma unroll
    for (int i = 0; i < 16; ++i) {
        int p2 = q + 4*i;
        dst[(b*HWA + t0 + p2)*CC + c2] = tile[p2][c2];  // coalesced over c2
    }
}

// ---------- 2. weight transpose OIHW -> [ky][kx][ic][oc] ----------
__global__ void k_wtrans(const float* __restrict__ w, float* __restrict__ wt, int OC) {
    int i = blockIdx.x*256 + threadIdx.x;
    int n = OC*288;
    if (i >= n) return;
    int kx = i % 3;
    int ky = (i/3) % 3;
    int ic = (i/9) & 31;
    int oc = i / 288;
    wt[((ky*3+kx)*32 + ic)*OC + oc] = w[i];
}

// ---------- 3. grouped 3x3 conv (groups=2), 4 pixels per block ----------
__global__ void k_conv_g2(const float* __restrict__ xt, const float* __restrict__ wt,
                          const float* __restrict__ bias, float* __restrict__ out, int OC) {
    __shared__ float patch[3*6*64];    // rows h-1..h+1, cols w0-1..w0+4, 64 ch
    int blk = blockIdx.x;              // BB*56*14
    int b   = blk / (56*14);
    int rem = blk % (56*14);
    int h   = rem / 14;
    int w0  = (rem % 14) * 4;
    int tid = threadIdx.x;             // 128

    for (int i = tid; i < 1152; i += 128) {
        int c   = i & 63;
        int col = (i >> 6) % 6;
        int r   = i / 384;
        int y = h - 1 + r;
        int x = w0 - 1 + col;
        float v = 0.f;
        if (y >= 0 && y < HH && x >= 0 && x < WW)
            v = xt[(b*HWA + y*WW + x)*CC + c];
        patch[i] = v;
    }
    __syncthreads();

    int oc = tid;
    if (oc < OC) {
        int half  = OC >> 1;
        int cbase = (oc >= half) ? 32 : 0;
        float bs = bias[oc];
        float acc0 = bs, acc1 = bs, acc2 = bs, acc3 = bs;
        for (int ky = 0; ky < 3; ++ky) {
            for (int kx = 0; kx < 3; ++kx) {
                const float* wp = wt + ((ky*3+kx)*32)*OC + oc;
                const float* pp = patch + ky*384 + kx*64 + cbase;
#pragma unroll
                for (int ic = 0; ic < 32; ++ic) {
                    float wv  = wp[ic*OC];      // coalesced over oc lanes
                    acc0 += wv * pp[ic];
                    acc1 += wv * pp[64  + ic];
                    acc2 += wv * pp[128 + ic];
                    acc3 += wv * pp[192 + ic];
                }
            }
        }
        int base = (b*OC + oc)*HWA + h*WW + w0;   // 16B aligned (w0 % 4 == 0)
        float4 r; r.x = acc0; r.y = acc1; r.z = acc2; r.w = acc3;
        *reinterpret_cast<float4*>(out + base) = r;
    }
}

// ---------- 4. deformable depthwise conv, NHWC in/out ----------
template<int K, int KS, int PAD>
__global__ void k_deform(const float* __restrict__ src, const float* __restrict__ off,
                         const float* __restrict__ wg, const float* __restrict__ bias,
                         float* __restrict__ out) {
    __shared__ float lw[K*64];         // [t][c], conflict-free lane reads
    int tid = threadIdx.x + threadIdx.y*64;   // 256
    for (int i = tid; i < K*64; i += 256) {
        int c = i / K, t = i % K;
        lw[t*64 + c] = wg[i];
    }
    __syncthreads();

    int blk = blockIdx.x;              // BB * (HWA/4)
    int b   = blk / (HWA/4);
    int hw  = (blk % (HWA/4))*4 + threadIdx.y;
    int h   = hw / WW, w = hw % WW;
    int c   = threadIdx.x;

    const float* offb = off + (size_t)(b*2*K)*HWA + hw;
    const float* srcb = src + (size_t)b*HWA*CC + c;

    float acc = 0.f;
    for (int t = 0; t < K; ++t) {
        int ky = t / KS, kx = t % KS;
        float oy = offb[(2*t  )*HWA];  // wave-broadcast
        float ox = offb[(2*t+1)*HWA];
        float py = (float)(h - PAD + 3*ky) + oy;
        float px = (float)(w - PAD + 3*kx) + ox;
        float y0f = floorf(py), x0f = floorf(px);
        float ly = py - y0f, lx = px - x0f;
        float hy = 1.f - ly, hx = 1.f - lx;
        int y0 = (int)y0f, x0 = (int)x0f;
        bool yi0 = (y0   >= 0) && (y0   < HH);
        bool yi1 = (y0+1 >= 0) && (y0+1 < HH);
        bool xi0 = (x0   >= 0) && (x0   < WW);
        bool xi1 = (x0+1 >= 0) && (x0+1 < WW);
        float v00 = 0.f, v01 = 0.f, v10 = 0.f, v11 = 0.f;
        int base = (y0*WW + x0)*CC;
        if (yi0 && xi0) v00 = srcb[base];
        if (yi0 && xi1) v01 = srcb[base + CC];
        if (yi1 && xi0) v10 = srcb[base + WW*CC];
        if (yi1 && xi1) v11 = srcb[base + WW*CC + CC];
        float val = hy*(hx*v00 + lx*v01) + ly*(hx*v10 + lx*v11);
        acc += val * lw[t*64 + c];
    }
    out[((size_t)b*HWA + hw)*CC + c] = acc + bias[c];
}

// ---------- 5a. GAP stage 1: partial sums over 64-pixel chunks ----------
__global__ void k_gap1(const float* __restrict__ o1, const float* __restrict__ o2,
                       float* __restrict__ partial) {
    __shared__ float red[4][64];
    int blk   = blockIdx.x;            // BB*2*49
    int chunk = blk % 49;
    int f     = (blk / 49) & 1;
    int b     = blk / 98;
    const float* src = f ? o2 : o1;
    int tid = threadIdx.x;             // 256
    int c = tid & 63, s = tid >> 6;
    int hw0 = chunk * 64;
    float sum = 0.f;
#pragma unroll
    for (int i = 0; i < 16; ++i) {
        int hw = hw0 + s + 4*i;
        sum += src[((size_t)b*HWA + hw)*CC + c];   // coalesced 256B per wave
    }
    red[s][c] = sum;
    __syncthreads();
    if (s == 0)
        partial[((size_t)(b*2 + f)*49 + chunk)*64 + c]
            = red[0][c] + red[1][c] + red[2][c] + red[3][c];
}

// ---------- 5b. GAP stage 2: reduce 49 chunks ----------
__global__ void k_gap2(const float* __restrict__ partial, float* __restrict__ gap) {
    int bf = blockIdx.x;               // 8
    int c  = threadIdx.x;              // 64
    const float* p = partial + (size_t)bf*49*64 + c;
    float tot = 0.f;
    for (int j = 0; j < 49; ++j) tot += p[j*64];
    gap[bf*64 + c] = tot * (1.f/HWA);
}

// ---------- 6. softmax gate + combine, NHWC -> NCHW ----------
__global__ void k_combine(const float* __restrict__ o1, const float* __restrict__ o2,
                          const float* __restrict__ gap, float* __restrict__ out) {
    __shared__ float tile[64][65];
    int blk = blockIdx.x;              // BB * (HWA/64)
    int b   = blk / (HWA/64);
    int t0  = (blk % (HWA/64)) * 64;
    int tid = threadIdx.x;             // 256
    int c = tid & 63, q = tid >> 6;

    float g1 = gap[(b*2+0)*CC + c];
    float g2 = gap[(b*2+1)*CC + c];
    float m  = fmaxf(g1, g2);
    float e1 = expf(g1 - m), e2 = expf(g2 - m);
    float a1 = e1 / (e1 + e2), a2 = 1.f - a1;

#pragma unroll
    for (int i = 0; i < 16; ++i) {
        int p = q + 4*i;
        size_t idx = ((size_t)b*HWA + t0 + p)*CC + c;
        tile[p][c] = o1[idx]*a1 + o2[idx]*a2;
    }
    __syncthreads();
    int p2 = tid & 63;
#pragma unroll
    for (int i = 0; i < 16; ++i) {
        int c2 = q + 4*i;
        out[((size_t)b*CC + c2)*HWA + t0 + p2] = tile[p2][c2];
    }
}

extern "C" void kernel_launch(void* const* d_in, const int* in_sizes, int n_in,
                              void* d_out, int out_size, void* d_ws, size_t ws_size,
                              hipStream_t stream) {
    const float* x      = (const float*)d_in[0];
    const float* w_off3 = (const float*)d_in[1];
    const float* b_off3 = (const float*)d_in[2];
    const float* w_off2 = (const float*)d_in[3];
    const float* b_off2 = (const float*)d_in[4];
    const float* w7     = (const float*)d_in[5];
    const float* b7     = (const float*)d_in[6];
    const float* w5     = (const float*)d_in[7];
    const float* b5     = (const float*)d_in[8];
    float* out = (float*)d_out;

    float* ws   = (float*)d_ws;
    float* x_t  = ws;                     // 802816
    float* off3 = x_t  + 802816;          // 1229312
    float* off2 = off3 + 1229312;         // 627200
    float* out1 = off2 + 627200;          // 802816
    float* out2 = out1 + 802816;          // 802816
    float* gap  = out2 + 802816;          // 512
    float* wt3  = gap  + 512;             // 28224
    float* wt2  = wt3  + 28224;           // 14400
    float* gpart= wt2  + 14400;           // 8*49*64 = 25088
    size_t need = (size_t)(802816*3 + 1229312 + 627200 + 512 + 28224 + 14400 + 25088) * 4;
    if (ws_size < need) return;           // fail loudly via wrong output

    // x -> NHWC
    k_transpose<<<BB*(HWA/64), 256, 0, stream>>>(x, x_t);
    // weight transposes
    k_wtrans<<<(98*288 + 255)/256, 256, 0, stream>>>(w_off3, wt3, 98);
    k_wtrans<<<(50*288 + 255)/256, 256, 0, stream>>>(w_off2, wt2, 50);
    // offset convs
    k_conv_g2<<<BB*56*14, 128, 0, stream>>>(x_t, wt3, b_off3, off3, 98);
    k_conv_g2<<<BB*56*14, 128, 0, stream>>>(x_t, wt2, b_off2, off2, 50);
    // deform 1: k=7, pad=9, dil=3, src = x_t
    k_deform<49,7,9><<<BB*(HWA/4), dim3(64,4), 0, stream>>>(x_t, off3, w7, b7, out1);
    // deform 2: k=5, pad=6, dil=3, src = out1
    k_deform<25,5,6><<<BB*(HWA/4), dim3(64,4), 0, stream>>>(out1, off2, w5, b5, out2);
    // gate (two-stage deterministic reduction)
    k_gap1<<<BB*2*49, 256, 0, stream>>>(out1, out2, gpart);
    k_gap2<<<BB*2, 64, 0, stream>>>(gpart, gap);
    k_combine<<<BB*(HWA/64), 256, 0, stream>>>(out1, out2, gap, out);
}